// Round 5
// baseline (327.574 us; speedup 1.0000x reference)
//
#include <hip/hip_runtime.h>
#include <math.h>

#define BB 8
#define FF 256
#define SS 1024
#define KK 16
#define ITERS 5

typedef unsigned long long ull;

// ---------- wm: two-stage deterministic column-mean of w ----------
#define ICH 8
__global__ void wm_part_kernel(const float* __restrict__ w, float* __restrict__ part) {
    int j = blockIdx.x * 256 + threadIdx.x;
    int ic = blockIdx.y, b = blockIdx.z;
    const float* wp = w + (size_t)b * SS * SS + (size_t)ic * (SS / ICH) * SS + j;
    float s = 0.f;
#pragma unroll 8
    for (int i = 0; i < SS / ICH; ++i) s += wp[(size_t)i * SS];
    part[((size_t)ic * BB + b) * SS + j] = s;
}

__global__ void wm_final_kernel(const float* __restrict__ part, float* __restrict__ wm) {
    int t = blockIdx.x * blockDim.x + threadIdx.x;
    if (t >= BB * SS) return;
    int b = t / SS, j = t % SS;
    float s = 0.f;
#pragma unroll
    for (int ic = 0; ic < ICH; ++ic) s += part[((size_t)ic * BB + b) * SS + j];
    wm[t] = s * (1.0f / SS);
}

// ---------- d[b][i][j] = sum_f |x[b][f][i] - x[b][f][j]| ----------
// 1-wave blocks (fine-grained scheduling, no barriers), wave-private 64x32
// tile, 8x4 acc/lane, double-buffered global->LDS staging with vmcnt(6)
// so the next chunk's 6 loads stay in flight during compute.
// f accumulated ascending (bitwise-matches prior passing versions).
#define FCD 16
__device__ __forceinline__ void async_copy16(const float* g, const float* s) {
    __builtin_amdgcn_global_load_lds((const __attribute__((address_space(1))) void*)g,
                                     (__attribute__((address_space(3))) void*)s, 16, 0, 0);
}

__global__ __launch_bounds__(64, 4) void dist_kernel(const float* __restrict__ x,
                                                     float* __restrict__ d) {
    __shared__ float smem[3072];   // [A0 1024 | B0 512 | A1 1024 | B1 512] = 12 KB
    int lane = threadIdx.x;
    int b = blockIdx.y;
    int w = blockIdx.x;                 // 0..271 wave-tile id
    int it = 0, rem = w;
    while (rem >= 32 - 2 * it) { rem -= 32 - 2 * it; ++it; }
    int jt = 2 * it + rem;
    int i0 = it * 64, j0 = jt * 32;
    const float* xb = x + (size_t)b * FF * SS;
    float* db = d + (size_t)b * SS * SS;
    int ly = lane >> 3, lx = lane & 7;           // 8x8 lane grid
    int aFl = lane >> 4, aTk = (lane & 15) * 4;  // A staging: 4 f-rows x 64 tok/inst
    int bFl = lane >> 3, bTk = (lane & 7) * 4;   // B staging: 8 f-rows x 32 tok/inst

    float acc[8][4] = {};

    auto stage = [&](int c, int h) {
        float* A = smem + h * 1536;
        float* B = A + 1024;
        const float* base = xb + (size_t)c * FCD * SS;
#pragma unroll
        for (int ci = 0; ci < 4; ++ci)
            async_copy16(base + (size_t)(ci * 4 + aFl) * SS + i0 + aTk, A + ci * 256);
#pragma unroll
        for (int ci = 0; ci < 2; ++ci)
            async_copy16(base + (size_t)(ci * 8 + bFl) * SS + j0 + bTk, B + ci * 256);
    };
    auto compute = [&](int h) {
        const float* A = smem + h * 1536;
        const float* B = A + 1024;
#pragma unroll 4
        for (int f = 0; f < FCD; ++f) {
            const float* af = A + f * 64 + ly * 8;
            const float* bf = B + f * 32 + lx * 4;
            float4 a0 = *(const float4*)af;
            float4 a1 = *(const float4*)(af + 4);
            float4 bb = *(const float4*)bf;
            float av[8] = {a0.x, a0.y, a0.z, a0.w, a1.x, a1.y, a1.z, a1.w};
            float bv[4] = {bb.x, bb.y, bb.z, bb.w};
#pragma unroll
            for (int r = 0; r < 8; ++r)
#pragma unroll
                for (int c = 0; c < 4; ++c)
                    acc[r][c] += fabsf(av[r] - bv[c]);
        }
    };

    stage(0, 0);
#pragma unroll 1
    for (int k = 0; k < FF / FCD - 1; ++k) {
        // WAR: ds_reads of the buffer we are about to overwrite have retired
        asm volatile("s_waitcnt lgkmcnt(0)" ::: "memory");
        stage(k + 1, (k + 1) & 1);
        // wait only for chunk k's 6 loads; chunk k+1's 6 stay in flight
        asm volatile("s_waitcnt vmcnt(6)" ::: "memory");
        compute(k & 1);
    }
    asm volatile("s_waitcnt vmcnt(0)" ::: "memory");
    compute(1);   // chunk 15 -> buffer 1

    // direct tile: rows i0+ly*8+r, cols j0+lx*4
#pragma unroll
    for (int r = 0; r < 8; ++r) {
        float4 v = make_float4(acc[r][0], acc[r][1], acc[r][2], acc[r][3]);
        *(float4*)&db[(size_t)(i0 + ly * 8 + r) * SS + j0 + lx * 4] = v;
    }
    if (rem >= 2) {
        // mirror straight from registers (d bitwise symmetric)
#pragma unroll
        for (int c = 0; c < 4; ++c) {
            float4 lo = make_float4(acc[0][c], acc[1][c], acc[2][c], acc[3][c]);
            float4 hi = make_float4(acc[4][c], acc[5][c], acc[6][c], acc[7][c]);
            float* p = &db[(size_t)(j0 + lx * 4 + c) * SS + i0 + ly * 8];
            *(float4*)p = lo;
            *(float4*)(p + 4) = hi;
        }
    }
}

// ---------- topk (jax.lax.top_k) + initial assign + ctr-buffer init ----------
// wm > 0 strictly, so float bits are order-monotonic.
__global__ __launch_bounds__(1024) void topk_assign_kernel(const float* __restrict__ wm,
                                                           const float* __restrict__ d,
                                                           int* __restrict__ assign,
                                                           ull* __restrict__ ctrbuf) {
    int b = blockIdx.x;
    int tid = threadIdx.x;          // == token index
    int lane = tid & 63, wv = tid >> 6;
    // init the 5 per-iteration medoid atomic buffers for this batch
    if (tid < ITERS * KK) ctrbuf[(tid / KK) * BB * KK + b * KK + (tid % KK)] = ~0ull;
    __shared__ ull red[16];
    __shared__ int ctr_s[KK];
    float v = wm[b * SS + tid];
    // key: value-desc, tie -> smaller index (complemented idx, max-reduce)
    ull key = (((ull)__float_as_uint(v)) << 32) | (ull)(0xFFFFFFFFu - (unsigned)tid);
    for (int k = 0; k < KK; ++k) {
        ull kk = key;
#pragma unroll
        for (int off = 32; off; off >>= 1) {
            ull o = __shfl_down(kk, off, 64);
            if (o > kk) kk = o;
        }
        if (lane == 0) red[wv] = kk;
        __syncthreads();
        if (wv == 0) {
            ull k2 = (lane < 16) ? red[lane] : 0ull;
#pragma unroll
            for (int off = 8; off; off >>= 1) {
                ull o = __shfl_down(k2, off, 64);
                if (o > k2) k2 = o;
            }
            if (lane == 0) red[0] = k2;
        }
        __syncthreads();
        ull W = red[0];
        int widx = (int)(0xFFFFFFFFu - (unsigned)(W & 0xFFFFFFFFu));
        if (tid == widx) key = 0;            // remove winner
        if (tid == 0) ctr_s[k] = widx;
        __syncthreads();                      // protect red[] before next round
    }
    // initial assign: argmin_k d[ctr[k]][i] (d symmetric; coalesced over i)
    const float* db = d + (size_t)b * SS * SS;
    float bv = INFINITY;
    int bk = 0;
#pragma unroll
    for (int k = 0; k < KK; ++k) {
        float vv = db[(size_t)ctr_s[k] * SS + tid];
        if (vv < bv) { bv = vv; bk = k; }    // strict < keeps first k
    }
    assign[b * SS + tid] = bk;
}

// ---------- cost + medoid update fused ----------
// cost[b][i] = sum_{j: assign[j]==assign[i]} d[i][j]*wm[j]; then a single
// deterministic atomicMin of key = (cost_bits<<32 | i) into ctrn[b][assign[i]].
// min is order-independent -> result identical to a sequential scan.
__global__ __launch_bounds__(256) void cost_kernel(const float* __restrict__ d,
                                                   const float* __restrict__ wm,
                                                   const int* __restrict__ assign,
                                                   ull* __restrict__ ctrn) {
    int b = blockIdx.y;
    int i = blockIdx.x;
    int tid = threadIdx.x;
    int my = assign[b * SS + i];
    const float* drow = d + (size_t)b * SS * SS + (size_t)i * SS;
    const float* wb = wm + b * SS;
    const int* ab = assign + b * SS;
    float4 dv = *(const float4*)&drow[tid * 4];
    float4 wv = *(const float4*)&wb[tid * 4];
    int4 av = *(const int4*)&ab[tid * 4];
    float s = 0.f;
    s += (av.x == my) ? dv.x * wv.x : 0.f;
    s += (av.y == my) ? dv.y * wv.y : 0.f;
    s += (av.z == my) ? dv.z * wv.z : 0.f;
    s += (av.w == my) ? dv.w * wv.w : 0.f;
#pragma unroll
    for (int off = 32; off > 0; off >>= 1) s += __shfl_down(s, off, 64);
    __shared__ float ws_s[4];
    if ((tid & 63) == 0) ws_s[tid >> 6] = s;
    __syncthreads();
    if (tid == 0) {
        float c = (ws_s[0] + ws_s[1]) + (ws_s[2] + ws_s[3]);
        // cost >= 0 finite -> float bits order-monotonic
        ull key = (((ull)__float_as_uint(c)) << 32) | (unsigned)i;
        atomicMin(&ctrn[b * KK + my], key);
    }
}

// ---------- wide assign from packed ctr (empty cluster -> medoid 0) ----------
__global__ __launch_bounds__(256) void assign_from_kernel(const float* __restrict__ d,
                                                          const ull* __restrict__ ctrn,
                                                          int* __restrict__ assign) {
    int b = blockIdx.y;
    int i = blockIdx.x * 256 + threadIdx.x;
    const float* db = d + (size_t)b * SS * SS;
    float bv = INFINITY;
    int bk = 0;
#pragma unroll
    for (int k = 0; k < KK; ++k) {
        ull key = ctrn[b * KK + k];
        int c = (key == ~0ull) ? 0 : (int)(key & 0xFFFFFFFFu);
        float vv = db[(size_t)c * SS + i];
        if (vv < bv) { bv = vv; bk = k; }    // strict < keeps first k
    }
    assign[b * SS + i] = bk;
}

// ---------- out[b][f][k] = x[b][f][ctr[b][k]] ----------
__global__ void gather_kernel(const float* __restrict__ x, const ull* __restrict__ ctrn,
                              float* __restrict__ out) {
    int t = blockIdx.x * blockDim.x + threadIdx.x;
    if (t >= BB * FF * KK) return;
    int b = t / (FF * KK);
    int f = (t / KK) % FF;
    int k = t % KK;
    ull key = ctrn[b * KK + k];
    int c = (key == ~0ull) ? 0 : (int)(key & 0xFFFFFFFFu);
    out[t] = x[(size_t)b * FF * SS + (size_t)f * SS + c];
}

extern "C" void kernel_launch(void* const* d_in, const int* in_sizes, int n_in,
                              void* d_out, int out_size, void* d_ws, size_t ws_size,
                              hipStream_t stream) {
    const float* x = (const float*)d_in[0];   // [B,F,S]
    const float* w = (const float*)d_in[1];   // [B,S,S]
    float* out = (float*)d_out;               // [B,F,K]

    char* ws = (char*)d_ws;
    float* d = (float*)ws;                              // B*S*S floats = 33.55 MB
    size_t off = (size_t)BB * SS * SS * sizeof(float);
    float* wm = (float*)(ws + off);  off += (size_t)BB * SS * sizeof(float);
    int* assign = (int*)(ws + off);  off += (size_t)BB * SS * sizeof(int);
    off = (off + 15) & ~(size_t)15;
    ull* ctrbuf = (ull*)(ws + off);                     // [ITERS][B][K] packed medoids
    // wm_part scratch aliases d: consumed by wm_final before dist writes d
    float* part = (float*)ws;

    wm_part_kernel<<<dim3(SS / 256, ICH, BB), 256, 0, stream>>>(w, part);
    wm_final_kernel<<<(BB * SS + 255) / 256, 256, 0, stream>>>(part, wm);
    // 272 wave-tiles per batch, one wave per block
    dist_kernel<<<dim3(272, BB), 64, 0, stream>>>(x, d);
    topk_assign_kernel<<<BB, 1024, 0, stream>>>(wm, d, assign, ctrbuf);
    for (int itr = 0; itr < ITERS; ++itr) {
        ull* ctrn = ctrbuf + (size_t)itr * BB * KK;
        cost_kernel<<<dim3(SS, BB), 256, 0, stream>>>(d, wm, assign, ctrn);
        if (itr < ITERS - 1)
            assign_from_kernel<<<dim3(SS / 256, BB), 256, 0, stream>>>(d, ctrn, assign);
        else
            gather_kernel<<<(BB * FF * KK + 255) / 256, 256, 0, stream>>>(x, ctrn, out);
    }
}

// Round 6
// 240.304 us; speedup vs baseline: 1.3632x; 1.3632x over previous
//
#include <hip/hip_runtime.h>
#include <math.h>

#define BB 8
#define FF 256
#define SS 1024
#define KK 16
#define ITERS 5

typedef unsigned long long ull;

// ---------- wm: two-stage deterministic column-mean of w ----------
#define ICH 8
__global__ void wm_part_kernel(const float* __restrict__ w, float* __restrict__ part) {
    int j = blockIdx.x * 256 + threadIdx.x;
    int ic = blockIdx.y, b = blockIdx.z;
    const float* wp = w + (size_t)b * SS * SS + (size_t)ic * (SS / ICH) * SS + j;
    float s = 0.f;
#pragma unroll 8
    for (int i = 0; i < SS / ICH; ++i) s += wp[(size_t)i * SS];
    part[((size_t)ic * BB + b) * SS + j] = s;
}

__global__ void wm_final_kernel(const float* __restrict__ part, float* __restrict__ wm) {
    int t = blockIdx.x * blockDim.x + threadIdx.x;
    if (t >= BB * SS) return;
    int b = t / SS, j = t % SS;
    float s = 0.f;
#pragma unroll
    for (int ic = 0; ic < ICH; ++ic) s += part[((size_t)ic * BB + b) * SS + j];
    wm[t] = s * (1.0f / SS);
}

// ---------- d[b][i][j] = sum_f |x[b][f][i] - x[b][f][j]| ----------
// 32x32 wave-tiles (528 triangular tiles/batch -> 4224 one-wave blocks,
// ~4 waves/SIMD for latency hiding), 4x4 acc/lane, double-buffered
// global->LDS staging with vmcnt(4). No barriers (1-wave blocks).
// f accumulated ascending (bitwise-matches all prior passing versions).
#define FCD 16
__device__ __forceinline__ void async_copy16(const float* g, const float* s) {
    __builtin_amdgcn_global_load_lds((const __attribute__((address_space(1))) void*)g,
                                     (__attribute__((address_space(3))) void*)s, 16, 0, 0);
}

__global__ __launch_bounds__(64, 4) void dist_kernel(const float* __restrict__ x,
                                                     float* __restrict__ d) {
    __shared__ float smem[2048];   // [A0 512 | B0 512 | A1 512 | B1 512] = 8 KB
    int lane = threadIdx.x;
    int b = blockIdx.y;
    int w = blockIdx.x;                 // 0..527 triangular tile id (32x32 tiles)
    int it = 0, rem = w;
    while (rem >= 32 - it) { rem -= 32 - it; ++it; }
    int jt = it + rem;
    int i0 = it * 32, j0 = jt * 32;
    const float* xb = x + (size_t)b * FF * SS;
    float* db = d + (size_t)b * SS * SS;
    int ly = lane >> 3, lx = lane & 7;           // 8x8 lane grid, 4x4 each
    int sFl = lane >> 3, sTk = (lane & 7) * 4;   // staging: 8 f-rows x 32 tok/inst

    float acc[4][4] = {};

    auto stage = [&](int c, int h) {
        float* A = smem + h * 1024;
        float* B = A + 512;
        const float* base = xb + (size_t)c * FCD * SS;
#pragma unroll
        for (int ci = 0; ci < 2; ++ci) {
            async_copy16(base + (size_t)(ci * 8 + sFl) * SS + i0 + sTk, A + ci * 256);
            async_copy16(base + (size_t)(ci * 8 + sFl) * SS + j0 + sTk, B + ci * 256);
        }
    };
    auto compute = [&](int h) {
        const float* A = smem + h * 1024;
        const float* B = A + 512;
#pragma unroll 4
        for (int f = 0; f < FCD; ++f) {
            float4 a = *(const float4*)(A + f * 32 + ly * 4);
            float4 bb = *(const float4*)(B + f * 32 + lx * 4);
            float av[4] = {a.x, a.y, a.z, a.w};
            float bv[4] = {bb.x, bb.y, bb.z, bb.w};
#pragma unroll
            for (int r = 0; r < 4; ++r)
#pragma unroll
                for (int c = 0; c < 4; ++c)
                    acc[r][c] += fabsf(av[r] - bv[c]);
        }
    };

    stage(0, 0);
#pragma unroll 1
    for (int k = 0; k < FF / FCD - 1; ++k) {
        // WAR: ds_reads of the buffer we are about to overwrite have retired
        asm volatile("s_waitcnt lgkmcnt(0)" ::: "memory");
        stage(k + 1, (k + 1) & 1);
        // wait only for chunk k's 4 loads; chunk k+1's 4 stay in flight
        asm volatile("s_waitcnt vmcnt(4)" ::: "memory");
        compute(k & 1);
    }
    asm volatile("s_waitcnt vmcnt(0)" ::: "memory");
    compute(1);   // chunk 15 -> buffer 1

    // direct tile: rows i0+ly*4+r, cols j0+lx*4
#pragma unroll
    for (int r = 0; r < 4; ++r) {
        float4 v = make_float4(acc[r][0], acc[r][1], acc[r][2], acc[r][3]);
        *(float4*)&db[(size_t)(i0 + ly * 4 + r) * SS + j0 + lx * 4] = v;
    }
    if (it != jt) {
        // mirror straight from registers (d bitwise symmetric)
#pragma unroll
        for (int c = 0; c < 4; ++c) {
            float4 v = make_float4(acc[0][c], acc[1][c], acc[2][c], acc[3][c]);
            *(float4*)&db[(size_t)(j0 + lx * 4 + c) * SS + i0 + ly * 4] = v;
        }
    }
}

// ---------- topk (jax.lax.top_k semantics) + initial assign, fused ----------
// wm > 0 strictly (means of uniform[0,1)), so float bits are order-monotonic.
__global__ __launch_bounds__(1024) void topk_assign_kernel(const float* __restrict__ wm,
                                                           const float* __restrict__ d,
                                                           int* __restrict__ assign) {
    int b = blockIdx.x;
    int tid = threadIdx.x;          // == token index
    int lane = tid & 63, wv = tid >> 6;
    __shared__ ull red[16];
    __shared__ int ctr_s[KK];
    float v = wm[b * SS + tid];
    // key: value-desc, tie -> smaller index (complemented idx, max-reduce)
    ull key = (((ull)__float_as_uint(v)) << 32) | (ull)(0xFFFFFFFFu - (unsigned)tid);
    for (int k = 0; k < KK; ++k) {
        ull kk = key;
#pragma unroll
        for (int off = 32; off; off >>= 1) {
            ull o = __shfl_down(kk, off, 64);
            if (o > kk) kk = o;
        }
        if (lane == 0) red[wv] = kk;
        __syncthreads();
        if (wv == 0) {
            ull k2 = (lane < 16) ? red[lane] : 0ull;
#pragma unroll
            for (int off = 8; off; off >>= 1) {
                ull o = __shfl_down(k2, off, 64);
                if (o > k2) k2 = o;
            }
            if (lane == 0) red[0] = k2;
        }
        __syncthreads();
        ull W = red[0];
        int widx = (int)(0xFFFFFFFFu - (unsigned)(W & 0xFFFFFFFFu));
        if (tid == widx) key = 0;            // remove winner
        if (tid == 0) ctr_s[k] = widx;
        __syncthreads();                      // protect red[] before next round
    }
    // initial assign: argmin_k d[ctr[k]][i] (d symmetric; coalesced over i)
    const float* db = d + (size_t)b * SS * SS;
    float bv = INFINITY;
    int bk = 0;
#pragma unroll
    for (int k = 0; k < KK; ++k) {
        float vv = db[(size_t)ctr_s[k] * SS + tid];
        if (vv < bv) { bv = vv; bk = k; }    // strict < keeps first k
    }
    assign[b * SS + tid] = bk;
}

// ---------- cost[b][i] = sum_{j: assign[j]==assign[i]} d[i][j]*wm[j] ----------
__global__ __launch_bounds__(256) void cost_kernel(const float* __restrict__ d,
                                                   const float* __restrict__ wm,
                                                   const int* __restrict__ assign,
                                                   float* __restrict__ cost) {
    int b = blockIdx.y;
    int i = blockIdx.x;
    int tid = threadIdx.x;
    int my = assign[b * SS + i];
    const float* drow = d + (size_t)b * SS * SS + (size_t)i * SS;
    const float* wb = wm + b * SS;
    const int* ab = assign + b * SS;
    float4 dv = *(const float4*)&drow[tid * 4];
    float4 wv = *(const float4*)&wb[tid * 4];
    int4 av = *(const int4*)&ab[tid * 4];
    float s = 0.f;
    s += (av.x == my) ? dv.x * wv.x : 0.f;
    s += (av.y == my) ? dv.y * wv.y : 0.f;
    s += (av.z == my) ? dv.z * wv.z : 0.f;
    s += (av.w == my) ? dv.w * wv.w : 0.f;
#pragma unroll
    for (int off = 32; off > 0; off >>= 1) s += __shfl_down(s, off, 64);
    __shared__ float ws_s[4];
    if ((tid & 63) == 0) ws_s[tid >> 6] = s;
    __syncthreads();
    if (tid == 0) cost[b * SS + i] = (ws_s[0] + ws_s[1]) + (ws_s[2] + ws_s[3]);
}

// ---------- medoid update (+ next assign, or final gather), fused ----------
__global__ __launch_bounds__(1024) void update_assign_kernel(
        const float* __restrict__ d, const float* __restrict__ cost,
        int* __restrict__ assign, const float* __restrict__ x,
        float* __restrict__ out, int last) {
    int b = blockIdx.x;
    int tid = threadIdx.x;
    int lane = tid & 63, wv = tid >> 6;
    __shared__ float cost_s[SS];
    __shared__ int assign_s[SS];
    __shared__ int ctr_s[KK];
    cost_s[tid] = cost[b * SS + tid];
    assign_s[tid] = assign[b * SS + tid];
    __syncthreads();
    // cost >= 0 finite, so float bits are order-monotonic
    ull best = ~0ull;
    int k = wv;   // 16 waves, 16 clusters
    for (int c = 0; c < SS / 64; ++c) {
        int i = c * 64 + lane;
        if (assign_s[i] == k) {
            ull key = (((ull)__float_as_uint(cost_s[i])) << 32) | (unsigned)i;
            if (key < best) best = key;
        }
    }
#pragma unroll
    for (int off = 32; off; off >>= 1) {
        ull o = __shfl_down(best, off, 64);
        if (o < best) best = o;
    }
    if (lane == 0) ctr_s[k] = (best == ~0ull) ? 0 : (int)(best & 0xFFFFFFFFu);
    __syncthreads();
    if (!last) {
        const float* db = d + (size_t)b * SS * SS;
        float bv = INFINITY;
        int bk = 0;
#pragma unroll
        for (int k2 = 0; k2 < KK; ++k2) {
            float vv = db[(size_t)ctr_s[k2] * SS + tid];
            if (vv < bv) { bv = vv; bk = k2; }
        }
        assign[b * SS + tid] = bk;
    } else {
        // out[b][f][k] = x[b][f][ctr[k]]
        for (int e = tid; e < FF * KK; e += 1024) {
            int f = e / KK, k2 = e % KK;
            out[((size_t)b * FF + f) * KK + k2] = x[((size_t)b * FF + f) * SS + ctr_s[k2]];
        }
    }
}

extern "C" void kernel_launch(void* const* d_in, const int* in_sizes, int n_in,
                              void* d_out, int out_size, void* d_ws, size_t ws_size,
                              hipStream_t stream) {
    const float* x = (const float*)d_in[0];   // [B,F,S]
    const float* w = (const float*)d_in[1];   // [B,S,S]
    float* out = (float*)d_out;               // [B,F,K]

    char* ws = (char*)d_ws;
    float* d = (float*)ws;                              // B*S*S floats = 33.55 MB
    size_t off = (size_t)BB * SS * SS * sizeof(float);
    float* wm = (float*)(ws + off);  off += (size_t)BB * SS * sizeof(float);
    int* assign = (int*)(ws + off);  off += (size_t)BB * SS * sizeof(int);
    float* cost = (float*)(ws + off);
    // wm_part scratch aliases d: consumed by wm_final before dist writes d
    float* part = (float*)ws;

    wm_part_kernel<<<dim3(SS / 256, ICH, BB), 256, 0, stream>>>(w, part);
    wm_final_kernel<<<(BB * SS + 255) / 256, 256, 0, stream>>>(part, wm);
    // 528 triangular 32x32 wave-tiles per batch, one wave per block
    dist_kernel<<<dim3(528, BB), 64, 0, stream>>>(x, d);
    topk_assign_kernel<<<BB, 1024, 0, stream>>>(wm, d, assign);
    for (int itr = 0; itr < ITERS; ++itr) {
        cost_kernel<<<dim3(SS, BB), 256, 0, stream>>>(d, wm, assign, cost);
        update_assign_kernel<<<BB, 1024, 0, stream>>>(d, cost, assign, x, out,
                                                      itr == ITERS - 1 ? 1 : 0);
    }
}